// Round 2
// baseline (323.335 us; speedup 1.0000x reference)
//
#include <hip/hip_runtime.h>

// Problem constants (from reference setup_inputs)
#define BQ 4
#define CQ 3
#define HQ 512
#define WQ 512
#define VN 12000
#define FN 24000
#define UHN 1024
#define UWN 1024

// ---------------------------------------------------------------------------
// Kernel 1 (fused): zero the valid-flag array AND project mesh vertices.
// Disjoint workspace regions, independent work -> one launch.
// mesh_img[b][v][2]; valid_t is [FN][BQ] bytes (transposed for u32 gather).
// ---------------------------------------------------------------------------
__global__ void init_kernel(const float* __restrict__ mesh,
                            const float* __restrict__ focal,
                            const float* __restrict__ princpt,
                            const float* __restrict__ R,
                            const float* __restrict__ t,
                            float* __restrict__ mesh_img,
                            unsigned int* __restrict__ valid_u32) {
    int idx = blockIdx.x * blockDim.x + threadIdx.x;
    if (idx < (BQ * FN) / 4) valid_u32[idx] = 0u;   // 24000 words
    if (idx >= BQ * VN) return;                     // 48000 projections
    int b = idx / VN;
    const float* Rb = R + b * 9;
    const float* tb = t + b * 3;
    float mx = mesh[idx * 3 + 0];
    float my = mesh[idx * 3 + 1];
    float mz = mesh[idx * 3 + 2];
    float cx = Rb[0] * mx + Rb[1] * my + Rb[2] * mz + tb[0];
    float cy = Rb[3] * mx + Rb[4] * my + Rb[5] * mz + tb[1];
    float cz = Rb[6] * mx + Rb[7] * my + Rb[8] * mz + tb[2];
    float x = cx / cz * focal[b * 2 + 0] + princpt[b * 2 + 0];
    float y = cy / cz * focal[b * 2 + 1] + princpt[b * 2 + 1];
    mesh_img[idx * 2 + 0] = x;
    mesh_img[idx * 2 + 1] = y;
}

// ---------------------------------------------------------------------------
// Kernel 2: scatter visibility flags from pix_to_face_xy into the
// TRANSPOSED layout valid_t[f][b].  The -1 sentinel maps to face FN-1,
// exactly like the reference's scatter.
// ---------------------------------------------------------------------------
__global__ void valid_kernel(const int* __restrict__ ptf_xy,
                             unsigned char* __restrict__ valid_t) {
    int idx = blockIdx.x * blockDim.x + threadIdx.x;
    if (idx >= BQ * HQ * WQ) return;
    int b = idx >> 18;                 // HQ*WQ = 262144 = 2^18
    int p = ptf_xy[idx];
    int l = (p != -1) ? (p - FN * b) : -1;
    if (l < 0) l += FN;
    valid_t[l * BQ + b] = 1;           // benign write race
}

// ---------------------------------------------------------------------------
// Kernel 3: main fused pass.  One thread per UV pixel; loops over batches
// and the 3 channels.  out[b][c][h][w].  Non-temporal stores for output.
// ---------------------------------------------------------------------------
__global__ void uv_kernel(const float* __restrict__ img,
                          const int* __restrict__ face,
                          const unsigned char* __restrict__ valid_t,
                          const float* __restrict__ mesh_img,
                          const int* __restrict__ ptf_uv,
                          const float* __restrict__ bary,
                          float* __restrict__ out) {
    int idx = blockIdx.x * blockDim.x + threadIdx.x;
    if (idx >= UHN * UWN) return;

    const size_t PLANE = (size_t)UHN * UWN;   // one output channel plane
    const int IMGPLANE = HQ * WQ;             // one img channel plane

    int puv = ptf_uv[idx];
    if (puv == -1) {
        // masked UV pixel: all batches/channels are -1
#pragma unroll
        for (int b = 0; b < BQ; ++b) {
            float* ob = out + (size_t)b * CQ * PLANE + idx;
            __builtin_nontemporal_store(-1.0f, ob);
            __builtin_nontemporal_store(-1.0f, ob + PLANE);
            __builtin_nontemporal_store(-1.0f, ob + 2 * PLANE);
        }
        return;
    }
    int pu = (puv < 0) ? puv + FN : puv;

    // one u32 load carries the visibility byte for all 4 batches
    unsigned int vmask = *(const unsigned int*)(valid_t + (size_t)pu * BQ);

    float w0 = bary[idx * 3 + 0];
    float w1 = bary[idx * 3 + 1];
    float w2 = bary[idx * 3 + 2];
    int v0 = face[pu * 3 + 0];
    int v1 = face[pu * 3 + 1];
    int v2 = face[pu * 3 + 2];

#pragma unroll
    for (int b = 0; b < BQ; ++b) {
        float* ob = out + (size_t)b * CQ * PLANE + idx;
        bool vis = ((vmask >> (8 * b)) & 0xffu) != 0u;
        if (!vis) {
            __builtin_nontemporal_store(-1.0f, ob);
            __builtin_nontemporal_store(-1.0f, ob + PLANE);
            __builtin_nontemporal_store(-1.0f, ob + 2 * PLANE);
            continue;
        }
        const float* mi = mesh_img + (size_t)b * VN * 2;
        float ux = w0 * mi[v0 * 2 + 0] + w1 * mi[v1 * 2 + 0] + w2 * mi[v2 * 2 + 0];
        float uy = w0 * mi[v0 * 2 + 1] + w1 * mi[v1 * 2 + 1] + w2 * mi[v2 * 2 + 1];

        // match reference's normalize -> denormalize round trip exactly
        float gx = ux / (float)(WQ - 1) * 2.0f - 1.0f;
        float gy = uy / (float)(HQ - 1) * 2.0f - 1.0f;
        float ix = (gx + 1.0f) * 0.5f * (float)(WQ - 1);
        float iy = (gy + 1.0f) * 0.5f * (float)(HQ - 1);

        float ix0 = floorf(ix), iy0 = floorf(iy);
        float wx1 = ix - ix0, wx0 = 1.0f - wx1;
        float wy1 = iy - iy0, wy0 = 1.0f - wy1;

        float xf[2] = {ix0, ix0 + 1.0f};
        float yf[2] = {iy0, iy0 + 1.0f};
        float wx[2] = {wx0, wx1};
        float wy[2] = {wy0, wy1};

        float acc0 = 0.f, acc1 = 0.f, acc2 = 0.f;
        const float* ib = img + (size_t)b * CQ * IMGPLANE;
#pragma unroll
        for (int ty = 0; ty < 2; ++ty) {
#pragma unroll
            for (int tx = 0; tx < 2; ++tx) {
                float wgt = wy[ty] * wx[tx];
                bool ok = (xf[tx] >= 0.0f) && (xf[tx] <= (float)(WQ - 1)) &&
                          (yf[ty] >= 0.0f) && (yf[ty] <= (float)(HQ - 1));
                float wv = ok ? wgt : 0.0f;
                int xi = (int)fminf(fmaxf(xf[tx], 0.0f), (float)(WQ - 1));
                int yi = (int)fminf(fmaxf(yf[ty], 0.0f), (float)(HQ - 1));
                const float* ip = ib + yi * WQ + xi;
                acc0 += ip[0] * wv;
                acc1 += ip[IMGPLANE] * wv;
                acc2 += ip[2 * IMGPLANE] * wv;
            }
        }
        __builtin_nontemporal_store(acc0, ob);
        __builtin_nontemporal_store(acc1, ob + PLANE);
        __builtin_nontemporal_store(acc2, ob + 2 * PLANE);
    }
}

// ---------------------------------------------------------------------------
extern "C" void kernel_launch(void* const* d_in, const int* in_sizes, int n_in,
                              void* d_out, int out_size, void* d_ws, size_t ws_size,
                              hipStream_t stream) {
    const float* img     = (const float*)d_in[0];
    const float* mesh    = (const float*)d_in[1];
    const int*   face    = (const int*)d_in[2];
    const float* focal   = (const float*)d_in[3];
    const float* princpt = (const float*)d_in[4];
    const float* R       = (const float*)d_in[5];
    const float* t       = (const float*)d_in[6];
    const int*   ptf_xy  = (const int*)d_in[7];
    const int*   ptf_uv  = (const int*)d_in[8];
    const float* bary    = (const float*)d_in[9];
    float* out = (float*)d_out;

    // workspace layout
    float* mesh_img = (float*)d_ws;                          // B*V*2 floats = 384000 B
    unsigned char* valid_t = (unsigned char*)d_ws + 384000;  // FN*B bytes  =  96000 B

    init_kernel<<<(BQ * VN + 255) / 256, 256, 0, stream>>>(
        mesh, focal, princpt, R, t, mesh_img, (unsigned int*)valid_t);

    valid_kernel<<<(BQ * HQ * WQ + 255) / 256, 256, 0, stream>>>(ptf_xy, valid_t);

    uv_kernel<<<(UHN * UWN + 255) / 256, 256, 0, stream>>>(
        img, face, valid_t, mesh_img, ptf_uv, bary, out);
}

// Round 3
// 200.629 us; speedup vs baseline: 1.6116x; 1.6116x over previous
//
#include <hip/hip_runtime.h>

// Problem constants (from reference setup_inputs)
#define BQ 4
#define CQ 3
#define HQ 512
#define WQ 512
#define VN 12000
#define FN 24000
#define UHN 1024
#define UWN 1024
#define IMGPLANE (HQ * WQ)

// workspace layout (byte offsets, all 16B-aligned)
#define MESHIMG_OFF 0u          // B*V*2 floats  = 384000 B
#define VALID_OFF   384000u     // FN*B bytes    =  96000 B
#define FD_OFF      480000u     // FN*B*8 floats = 3072000 B
#define IMGI_OFF    3552000u    // B*H*W*4 floats = 16777216 B
#define WS_NEED     (IMGI_OFF + (size_t)BQ * HQ * WQ * 4 * sizeof(float))

// ---------------------------------------------------------------------------
// Kernel 1 (fused): zero valid flags AND project mesh vertices.
// mesh_img[b][v][2]; valid_t is [FN][BQ] bytes.
// ---------------------------------------------------------------------------
__global__ void init_kernel(const float* __restrict__ mesh,
                            const float* __restrict__ focal,
                            const float* __restrict__ princpt,
                            const float* __restrict__ R,
                            const float* __restrict__ t,
                            float* __restrict__ mesh_img,
                            unsigned int* __restrict__ valid_u32) {
    int idx = blockIdx.x * blockDim.x + threadIdx.x;
    if (idx < (BQ * FN) / 4) valid_u32[idx] = 0u;   // 24000 words
    if (idx >= BQ * VN) return;                     // 48000 projections
    int b = idx / VN;
    const float* Rb = R + b * 9;
    const float* tb = t + b * 3;
    float mx = mesh[idx * 3 + 0];
    float my = mesh[idx * 3 + 1];
    float mz = mesh[idx * 3 + 2];
    float cx = Rb[0] * mx + Rb[1] * my + Rb[2] * mz + tb[0];
    float cy = Rb[3] * mx + Rb[4] * my + Rb[5] * mz + tb[1];
    float cz = Rb[6] * mx + Rb[7] * my + Rb[8] * mz + tb[2];
    float x = cx / cz * focal[b * 2 + 0] + princpt[b * 2 + 0];
    float y = cy / cz * focal[b * 2 + 1] + princpt[b * 2 + 1];
    mesh_img[idx * 2 + 0] = x;
    mesh_img[idx * 2 + 1] = y;
}

// ---------------------------------------------------------------------------
// Kernel 2: interleave img [b][c][y][x] -> img_i [b][y][x][4]  (c, pad)
// ---------------------------------------------------------------------------
__global__ void interleave_kernel(const float* __restrict__ img,
                                  float4* __restrict__ img_i) {
    int idx = blockIdx.x * blockDim.x + threadIdx.x;
    if (idx >= BQ * HQ * WQ) return;
    int b = idx >> 18;                       // HQ*WQ = 262144 = 2^18
    int p = idx & (IMGPLANE - 1);
    const float* ib = img + (size_t)b * CQ * IMGPLANE + p;
    float4 v;
    v.x = ib[0];
    v.y = ib[IMGPLANE];
    v.z = ib[2 * IMGPLANE];
    v.w = 0.0f;
    img_i[idx] = v;
}

// ---------------------------------------------------------------------------
// Kernel 3: scatter visibility flags (vectorized: 4 pixels / thread).
// valid_t[f][b]; the -1 sentinel maps to face FN-1 exactly like reference.
// ---------------------------------------------------------------------------
__global__ void valid_kernel(const int4* __restrict__ ptf_xy4,
                             unsigned char* __restrict__ valid_t) {
    int i = blockIdx.x * blockDim.x + threadIdx.x;
    if (i >= (BQ * HQ * WQ) / 4) return;
    int b = (i * 4) >> 18;                   // 4 consecutive pixels share batch
    int4 p4 = ptf_xy4[i];
    int p[4] = {p4.x, p4.y, p4.z, p4.w};
#pragma unroll
    for (int k = 0; k < 4; ++k) {
        int l = (p[k] != -1) ? (p[k] - FN * b) : -1;
        if (l < 0) l += FN;
        valid_t[l * BQ + b] = 1;             // benign write race
    }
}

// ---------------------------------------------------------------------------
// Kernel 4: build per-face gather table fd[f][b][8] =
//   {x0,y0, x1,y1, x2,y2, valid, 0}   (32B per (f,b); 128B per face)
// ---------------------------------------------------------------------------
__global__ void fd_kernel(const int* __restrict__ face,
                          const float* __restrict__ mesh_img,
                          const unsigned char* __restrict__ valid_t,
                          float4* __restrict__ fd) {
    int idx = blockIdx.x * blockDim.x + threadIdx.x;
    if (idx >= FN * BQ) return;
    int f = idx >> 2;
    int b = idx & 3;
    int v0 = face[f * 3 + 0];
    int v1 = face[f * 3 + 1];
    int v2 = face[f * 3 + 2];
    const float* mi = mesh_img + (size_t)b * VN * 2;
    float4 a, c;
    a.x = mi[v0 * 2 + 0]; a.y = mi[v0 * 2 + 1];
    a.z = mi[v1 * 2 + 0]; a.w = mi[v1 * 2 + 1];
    c.x = mi[v2 * 2 + 0]; c.y = mi[v2 * 2 + 1];
    c.z = valid_t[f * BQ + b] ? 1.0f : 0.0f;
    c.w = 0.0f;
    fd[idx * 2 + 0] = a;
    fd[idx * 2 + 1] = c;
}

// ---------------------------------------------------------------------------
// Kernel 5: main fused pass (fast path).  One thread per UV pixel.
// ---------------------------------------------------------------------------
__global__ void uv_kernel(const float4* __restrict__ img_i,
                          const float4* __restrict__ fd,
                          const int* __restrict__ ptf_uv,
                          const float* __restrict__ bary,
                          float* __restrict__ out) {
    int idx = blockIdx.x * blockDim.x + threadIdx.x;
    if (idx >= UHN * UWN) return;

    const size_t PLANE = (size_t)UHN * UWN;

    int puv = ptf_uv[idx];
    if (puv == -1) {
#pragma unroll
        for (int b = 0; b < BQ; ++b) {
            float* ob = out + (size_t)b * CQ * PLANE + idx;
            __builtin_nontemporal_store(-1.0f, ob);
            __builtin_nontemporal_store(-1.0f, ob + PLANE);
            __builtin_nontemporal_store(-1.0f, ob + 2 * PLANE);
        }
        return;
    }
    int pu = (puv < 0) ? puv + FN : puv;

    // one contiguous 128B region carries all 4 batches' face data
    const float4* fdp = fd + (size_t)pu * 8;
    float4 fa[BQ], fc[BQ];
#pragma unroll
    for (int b = 0; b < BQ; ++b) {
        fa[b] = fdp[2 * b + 0];
        fc[b] = fdp[2 * b + 1];
    }

    float w0 = bary[idx * 3 + 0];
    float w1 = bary[idx * 3 + 1];
    float w2 = bary[idx * 3 + 2];

#pragma unroll
    for (int b = 0; b < BQ; ++b) {
        float* ob = out + (size_t)b * CQ * PLANE + idx;
        if (fc[b].z == 0.0f) {               // invisible in this batch
            __builtin_nontemporal_store(-1.0f, ob);
            __builtin_nontemporal_store(-1.0f, ob + PLANE);
            __builtin_nontemporal_store(-1.0f, ob + 2 * PLANE);
            continue;
        }
        float ux = w0 * fa[b].x + w1 * fa[b].z + w2 * fc[b].x;
        float uy = w0 * fa[b].y + w1 * fa[b].w + w2 * fc[b].y;

        // match reference's normalize -> denormalize round trip exactly
        float gx = ux / (float)(WQ - 1) * 2.0f - 1.0f;
        float gy = uy / (float)(HQ - 1) * 2.0f - 1.0f;
        float ix = (gx + 1.0f) * 0.5f * (float)(WQ - 1);
        float iy = (gy + 1.0f) * 0.5f * (float)(HQ - 1);

        float ix0 = floorf(ix), iy0 = floorf(iy);
        float wx1 = ix - ix0, wx0 = 1.0f - wx1;
        float wy1 = iy - iy0, wy0 = 1.0f - wy1;

        float xf[2] = {ix0, ix0 + 1.0f};
        float yf[2] = {iy0, iy0 + 1.0f};
        float wx[2] = {wx0, wx1};
        float wy[2] = {wy0, wy1};

        const float4* ibi = img_i + (size_t)b * IMGPLANE;
        float acc0 = 0.f, acc1 = 0.f, acc2 = 0.f;
#pragma unroll
        for (int ty = 0; ty < 2; ++ty) {
#pragma unroll
            for (int tx = 0; tx < 2; ++tx) {
                float wgt = wy[ty] * wx[tx];
                bool ok = (xf[tx] >= 0.0f) && (xf[tx] <= (float)(WQ - 1)) &&
                          (yf[ty] >= 0.0f) && (yf[ty] <= (float)(HQ - 1));
                float wv = ok ? wgt : 0.0f;
                int xi = (int)fminf(fmaxf(xf[tx], 0.0f), (float)(WQ - 1));
                int yi = (int)fminf(fmaxf(yf[ty], 0.0f), (float)(HQ - 1));
                float4 v = ibi[yi * WQ + xi];
                acc0 += v.x * wv;
                acc1 += v.y * wv;
                acc2 += v.z * wv;
            }
        }
        __builtin_nontemporal_store(acc0, ob);
        __builtin_nontemporal_store(acc1, ob + PLANE);
        __builtin_nontemporal_store(acc2, ob + 2 * PLANE);
    }
}

// ---------------------------------------------------------------------------
// Fallback main pass (round-1 version) used when ws_size is too small.
// ---------------------------------------------------------------------------
__global__ void uv_kernel_fb(const float* __restrict__ img,
                             const int* __restrict__ face,
                             const unsigned char* __restrict__ valid_t,
                             const float* __restrict__ mesh_img,
                             const int* __restrict__ ptf_uv,
                             const float* __restrict__ bary,
                             float* __restrict__ out) {
    int idx = blockIdx.x * blockDim.x + threadIdx.x;
    if (idx >= UHN * UWN) return;
    const size_t PLANE = (size_t)UHN * UWN;
    int puv = ptf_uv[idx];
    if (puv == -1) {
#pragma unroll
        for (int b = 0; b < BQ; ++b) {
            float* ob = out + (size_t)b * CQ * PLANE + idx;
            __builtin_nontemporal_store(-1.0f, ob);
            __builtin_nontemporal_store(-1.0f, ob + PLANE);
            __builtin_nontemporal_store(-1.0f, ob + 2 * PLANE);
        }
        return;
    }
    int pu = (puv < 0) ? puv + FN : puv;
    unsigned int vmask = *(const unsigned int*)(valid_t + (size_t)pu * BQ);
    float w0 = bary[idx * 3 + 0];
    float w1 = bary[idx * 3 + 1];
    float w2 = bary[idx * 3 + 2];
    int v0 = face[pu * 3 + 0];
    int v1 = face[pu * 3 + 1];
    int v2 = face[pu * 3 + 2];
#pragma unroll
    for (int b = 0; b < BQ; ++b) {
        float* ob = out + (size_t)b * CQ * PLANE + idx;
        bool vis = ((vmask >> (8 * b)) & 0xffu) != 0u;
        if (!vis) {
            __builtin_nontemporal_store(-1.0f, ob);
            __builtin_nontemporal_store(-1.0f, ob + PLANE);
            __builtin_nontemporal_store(-1.0f, ob + 2 * PLANE);
            continue;
        }
        const float* mi = mesh_img + (size_t)b * VN * 2;
        float ux = w0 * mi[v0 * 2 + 0] + w1 * mi[v1 * 2 + 0] + w2 * mi[v2 * 2 + 0];
        float uy = w0 * mi[v0 * 2 + 1] + w1 * mi[v1 * 2 + 1] + w2 * mi[v2 * 2 + 1];
        float gx = ux / (float)(WQ - 1) * 2.0f - 1.0f;
        float gy = uy / (float)(HQ - 1) * 2.0f - 1.0f;
        float ix = (gx + 1.0f) * 0.5f * (float)(WQ - 1);
        float iy = (gy + 1.0f) * 0.5f * (float)(HQ - 1);
        float ix0 = floorf(ix), iy0 = floorf(iy);
        float wx1 = ix - ix0, wx0 = 1.0f - wx1;
        float wy1 = iy - iy0, wy0 = 1.0f - wy1;
        float xf[2] = {ix0, ix0 + 1.0f};
        float yf[2] = {iy0, iy0 + 1.0f};
        float wx[2] = {wx0, wx1};
        float wy[2] = {wy0, wy1};
        float acc0 = 0.f, acc1 = 0.f, acc2 = 0.f;
        const float* ib = img + (size_t)b * CQ * IMGPLANE;
#pragma unroll
        for (int ty = 0; ty < 2; ++ty) {
#pragma unroll
            for (int tx = 0; tx < 2; ++tx) {
                float wgt = wy[ty] * wx[tx];
                bool ok = (xf[tx] >= 0.0f) && (xf[tx] <= (float)(WQ - 1)) &&
                          (yf[ty] >= 0.0f) && (yf[ty] <= (float)(HQ - 1));
                float wv = ok ? wgt : 0.0f;
                int xi = (int)fminf(fmaxf(xf[tx], 0.0f), (float)(WQ - 1));
                int yi = (int)fminf(fmaxf(yf[ty], 0.0f), (float)(HQ - 1));
                const float* ip = ib + yi * WQ + xi;
                acc0 += ip[0] * wv;
                acc1 += ip[IMGPLANE] * wv;
                acc2 += ip[2 * IMGPLANE] * wv;
            }
        }
        __builtin_nontemporal_store(acc0, ob);
        __builtin_nontemporal_store(acc1, ob + PLANE);
        __builtin_nontemporal_store(acc2, ob + 2 * PLANE);
    }
}

// ---------------------------------------------------------------------------
extern "C" void kernel_launch(void* const* d_in, const int* in_sizes, int n_in,
                              void* d_out, int out_size, void* d_ws, size_t ws_size,
                              hipStream_t stream) {
    const float* img     = (const float*)d_in[0];
    const float* mesh    = (const float*)d_in[1];
    const int*   face    = (const int*)d_in[2];
    const float* focal   = (const float*)d_in[3];
    const float* princpt = (const float*)d_in[4];
    const float* R       = (const float*)d_in[5];
    const float* t       = (const float*)d_in[6];
    const int*   ptf_xy  = (const int*)d_in[7];
    const int*   ptf_uv  = (const int*)d_in[8];
    const float* bary    = (const float*)d_in[9];
    float* out = (float*)d_out;

    unsigned char* ws = (unsigned char*)d_ws;
    float*         mesh_img = (float*)(ws + MESHIMG_OFF);
    unsigned char* valid_t  = ws + VALID_OFF;
    float4*        fd       = (float4*)(ws + FD_OFF);
    float4*        img_i    = (float4*)(ws + IMGI_OFF);

    init_kernel<<<(BQ * VN + 255) / 256, 256, 0, stream>>>(
        mesh, focal, princpt, R, t, mesh_img, (unsigned int*)valid_t);

    valid_kernel<<<((BQ * HQ * WQ / 4) + 255) / 256, 256, 0, stream>>>(
        (const int4*)ptf_xy, valid_t);

    if (ws_size >= WS_NEED) {
        interleave_kernel<<<(BQ * HQ * WQ + 255) / 256, 256, 0, stream>>>(img, img_i);

        fd_kernel<<<(FN * BQ + 255) / 256, 256, 0, stream>>>(
            face, mesh_img, valid_t, fd);

        uv_kernel<<<(UHN * UWN + 255) / 256, 256, 0, stream>>>(
            img_i, fd, ptf_uv, bary, out);
    } else {
        uv_kernel_fb<<<(UHN * UWN + 255) / 256, 256, 0, stream>>>(
            img, face, valid_t, mesh_img, ptf_uv, bary, out);
    }
}